// Round 3
// baseline (333.070 us; speedup 1.0000x reference)
//
#include <hip/hip_runtime.h>
#include <cmath>

// SSIM over (32,3,512,512) f32 pairs, 11x11 separable gaussian, valid conv,
// scalar mean output. Round 8: occupancy lever. R6/R7 proved the compiler
// re-sinks prefetch loads at IR level (VGPR stuck at 60, no pipelining), so
// latency must be hidden by TLP instead of ILP. Band shrunk TYB 64->24
// (INR=34, hS = 34*33*16 = 17952 B): 8 blocks/CU (wave-capped, was 4
// LDS-capped), __launch_bounds__(256,8) caps VGPR at 64 (demand ~52-56).
// Phase-A tasks 272 = 256+16 -> near-perfect balance (was 592=2*256+80).
// Costs: vertical halo refetch 34/24 = 1.42x (FETCH ~275 MB, still cheap at
// 6.3 TB/s), Phase-B 4.33 LDS reads/output (LDS pipe parallel to VALU).
// Bit-swapped Phase-A task map + 33-f4 row stride keep writes/reads
// conflict-free exactly as in R4/R5 (maps are geometry-independent).

#define HH 512
#define WW 512
#define OH 502           // 512 - 11 + 1
#define OW 502
#define NC 96            // 32 * 3
#define TXS 32           // strip width (output cols)
#define TYB 24           // band height (output rows)
#define INR 34           // h-buffer rows = TYB + 10
#define HP4 33           // row stride in float4s (528 B -> 4-bank row rotation)
#define GX 16
#define GY 21            // 21 * 24 = 504 >= 502 output rows
#define NTASK (INR * 8)  // 272 Phase-A tasks (4 h-cols each)
#define NSLOT 64         // f64 accumulator slots, 64 B apart

typedef float f4 __attribute__((ext_vector_type(4)));

struct GaussW { float g[11]; };

static __device__ __forceinline__ f4 sp(float s) { return (f4){s, s, s, s}; }

__global__ __launch_bounds__(256, 8) void ssim_kernel(
        const float* __restrict__ X, const float* __restrict__ Y,
        double* __restrict__ acc, GaussW gw) {
    // hS[r][c] = f4(conv_h(x), conv_h(y), conv_h(x^2+y^2), conv_h(x*y)), raw
    // domain. 34*33*16 = 17952 B -> 8 blocks/CU (32-wave cap).
    __shared__ f4 hS[INR][HP4];
    __shared__ double wsum[4];

    const int tid = threadIdx.x;
    const int R0 = blockIdx.y * TYB;
    const int C0 = blockIdx.x * TXS;
    const float* Xp = X + (size_t)blockIdx.z * (HH * WW);
    const float* Yp = Y + (size_t)blockIdx.z * (HH * WW);
    const bool edge = (blockIdx.x == GX - 1);    // reads would pass col 511

    // Task map puts row in the LOW 3 bits: an 8-lane LDS service phase sees 8
    // different rows -> write banks 4*(r+c) disjoint -> conflict-free.
    auto dec = [&](int t, int& r, int& cg) {
        if (t < 256) { r = (t & 7) | ((t >> 6) << 3); cg = (t >> 3) & 7; }
        else         { int tt = t - 256; r = 32 + (tt & 1); cg = (tt >> 1) & 7; }
    };

    // Load one task's payload (8 float4s), h-conv it, store 4 f4 to LDS.
    auto task = [&](int r, int cg) {
        const int gr = min(R0 + r, HH - 1);      // clamp feeds masked rows only
        const float* xrow = Xp + gr * WW;
        const float* yrow = Yp + gr * WW;
        const int gc = C0 + 4 * cg;              // f4-aligned

        float xv[16], yv[16];
        if (!edge) {
            const float4* x4 = (const float4*)(xrow + gc);
            const float4* y4 = (const float4*)(yrow + gc);
            float4 a0 = x4[0], a1 = x4[1], a2 = x4[2], a3 = x4[3];
            float4 b0 = y4[0], b1 = y4[1], b2 = y4[2], b3 = y4[3];
            xv[0]=a0.x; xv[1]=a0.y; xv[2]=a0.z; xv[3]=a0.w;
            xv[4]=a1.x; xv[5]=a1.y; xv[6]=a1.z; xv[7]=a1.w;
            xv[8]=a2.x; xv[9]=a2.y; xv[10]=a2.z; xv[11]=a2.w;
            xv[12]=a3.x; xv[13]=a3.y; xv[14]=a3.z; xv[15]=a3.w;
            yv[0]=b0.x; yv[1]=b0.y; yv[2]=b0.z; yv[3]=b0.w;
            yv[4]=b1.x; yv[5]=b1.y; yv[6]=b1.z; yv[7]=b1.w;
            yv[8]=b2.x; yv[9]=b2.y; yv[10]=b2.z; yv[11]=b2.w;
            yv[12]=b3.x; yv[13]=b3.y; yv[14]=b3.z; yv[15]=b3.w;
        } else {
            #pragma unroll
            for (int i = 0; i < 16; ++i) {       // clamped cols feed masked
                int c = min(gc + i, WW - 1);     // outputs only (c >= 502)
                xv[i] = xrow[c];
                yv[i] = yrow[c];
            }
        }

        f4 a0v = sp(0.f), a1v = sp(0.f), a2v = sp(0.f), a3v = sp(0.f);
        #pragma unroll
        for (int k = 0; k < 14; ++k) {
            float x = xv[k], y = yv[k];
            f4 P;
            P.x = x; P.y = y;
            P.z = fmaf(x, x, y * y);             // raw domain (sum(g)=1 lets
            P.w = x * y;                         // normalization fold into epi)
            #pragma unroll
            for (int j = 0; j < 4; ++j) {
                int u = k - j;
                if (u >= 0 && u < 11) {          // statically resolved
                    f4 G = sp(gw.g[u]);
                    if (j == 0) a0v = __builtin_elementwise_fma(G, P, a0v);
                    if (j == 1) a1v = __builtin_elementwise_fma(G, P, a1v);
                    if (j == 2) a2v = __builtin_elementwise_fma(G, P, a2v);
                    if (j == 3) a3v = __builtin_elementwise_fma(G, P, a3v);
                }
            }
        }
        hS[r][4 * cg + 0] = a0v;                 // conflict-free b128 writes
        hS[r][4 * cg + 1] = a1v;
        hS[r][4 * cg + 2] = a2v;
        hS[r][4 * cg + 3] = a3v;
    };

    // ---- Phase A: 272 tasks / 256 threads; threads 0..15 take a second one.
    {
        int r, cg;
        dec(tid, r, cg);
        task(r, cg);
        if (tid < NTASK - 256) {                 // tid < 16
            dec(tid + 256, r, cg);
            task(r, cg);
        }
    }
    __syncthreads();

    // ---- Phase B: vertical 11-tap conv + SSIM. 256 threads, 1 col x 3 rows.
    // Read: 8-lane phase shares a row, cols 0..7(+8m) -> banks 4(r+c) disjoint.
    const int c  = tid & 31;
    const int rb = (tid >> 5) * 3;               // 0,3,...,21
    f4 A[3];
    #pragma unroll
    for (int j = 0; j < 3; ++j) A[j] = sp(0.f);
    #pragma unroll
    for (int k = 0; k < 13; ++k) {               // rows rb..rb+12 feed rb..rb+2
        f4 v = hS[rb + k][c];                    // one ds_read_b128 per tap-row
        #pragma unroll
        for (int j = 0; j < 3; ++j) {
            int u = k - j;
            if (u >= 0 && u < 11) {
                f4 G = sp(gw.g[u]);
                A[j] = __builtin_elementwise_fma(G, v, A[j]);
            }
        }
    }

    // Epilogue: raw-domain fixup. With u=(x+1)/2: 2*mu = cx+1,
    // sigma1^2+sigma2^2 = (cs - cx^2 - cy^2)/4, sigma12 = (cp - cx*cy)/4.
    const float C1 = 1.0e-4f;
    const float C2 = 9.0e-4f;
    float nn[3], dd[3];
    #pragma unroll
    for (int j = 0; j < 3; ++j) {
        f4 v = A[j];
        float t1 = v.x + 1.f, t2 = v.y + 1.f;    // 2*mu1, 2*mu2
        float num1 = fmaf(t1 * t2, 0.5f, C1);    // 2*mu1*mu2 + C1
        float den1 = fmaf(fmaf(t2, t2, t1 * t1), 0.25f, C1);
        float num2 = fmaf(v.w - v.x * v.y, 0.5f, C2);   // 2*sigma12 + C2
        float den2 = fmaf(v.z - fmaf(v.x, v.x, v.y * v.y), 0.25f, C2);
        bool valid = (R0 + rb + j < OH) & (C0 + c < OW);
        nn[j] = valid ? num1 * num2 : 0.f;
        dd[j] = valid ? den1 * den2 : 1.f;
    }
    // 1 divide for 3 outputs: common denominator
    // (dd >= C1*C2 ~ 1e-7; 3-products >= ~7e-22 stay normal in f32)
    float d01 = dd[0] * dd[1];
    float s01 = fmaf(nn[0], dd[1], nn[1] * dd[0]);
    float num = fmaf(s01, dd[2], nn[2] * d01);
    float den = d01 * dd[2];
    double tsum = (double)(num / den);

    // block reduction (double) + one f64 atomic into a strided slot
    #pragma unroll
    for (int off = 32; off > 0; off >>= 1)
        tsum += __shfl_down(tsum, off, 64);
    if ((tid & 63) == 0) wsum[tid >> 6] = tsum;
    __syncthreads();
    if (tid == 0) {
        int slot = (blockIdx.x + blockIdx.y * GX + blockIdx.z * GX * GY) & (NSLOT - 1);
        atomicAdd(&acc[slot * 8], wsum[0] + wsum[1] + wsum[2] + wsum[3]);
    }
}

__global__ void ssim_finalize(const double* __restrict__ acc,
                              float* __restrict__ out) {
    int lane = threadIdx.x;                      // 64 threads, one slot each
    double t = acc[lane * 8];
    #pragma unroll
    for (int off = 32; off > 0; off >>= 1)
        t += __shfl_down(t, off, 64);
    if (lane == 0)
        out[0] = (float)(t * (1.0 / (double)((long long)NC * OH * OW)));
}

extern "C" void kernel_launch(void* const* d_in, const int* in_sizes, int n_in,
                              void* d_out, int out_size, void* d_ws, size_t ws_size,
                              hipStream_t stream) {
    const float* X = (const float*)d_in[0];
    const float* Y = (const float*)d_in[1];
    float* out = (float*)d_out;
    double* acc = (double*)d_ws;                 // 64 slots x 64 B = 4 KB

    // d_ws is re-poisoned to 0xAA before every timed launch: zero the slots.
    hipMemsetAsync(d_ws, 0, NSLOT * 64, stream);

    // Gaussian weights (win=11, sigma=1.5), computed in f64, passed by value.
    GaussW gw;
    {
        double g[11], s = 0.0;
        for (int i = 0; i < 11; ++i) {
            double d = (double)(i - 5);
            g[i] = exp(-d * d / (2.0 * 1.5 * 1.5));
            s += g[i];
        }
        for (int i = 0; i < 11; ++i) gw.g[i] = (float)(g[i] / s);
    }

    dim3 grid(GX, GY, NC);
    ssim_kernel<<<grid, dim3(256), 0, stream>>>(X, Y, acc, gw);
    ssim_finalize<<<1, dim3(64), 0, stream>>>(acc, out);
}

// Round 4
// 330.180 us; speedup vs baseline: 1.0088x; 1.0088x over previous
//
#include <hip/hip_runtime.h>
#include <cmath>

// SSIM over (32,3,512,512) f32 pairs, 11x11 separable gaussian, valid conv,
// scalar mean output. Round 9: inline-asm software pipeline in Phase A.
// History: R6 (plain prefetch) and R7 (sched_barrier) were both defeated --
// the compiler re-sinks prefetch loads at IR level (VGPR stuck at 60).
// R8 (8 blocks/CU) proved TLP can't fill the stall either: occupancy 80%,
// VALUBusy unchanged 43%, dur +22% -- waves convoy on the same load burst.
// Fix: loads issued via asm volatile global_load_dwordx4 and consumed via
// asm volatile s_waitcnt vmcnt(N) that threads the payload registers as
// "+v" operands -- data flow pins load->wait->use, compiler cannot reorder.
// Geometry retuned: TYB=54 -> 64 h-rows -> NTASK=512=2x256, perfect 2
// tasks/thread (uniform waitcnt counts, no tail imbalance). Per thread:
// issue 16 loads (16 KB/wave MLP), vmcnt(8), conv(t0), vmcnt(0), conv(t1).
// hS = 66*33*16 = 34.8 KB -> 4 blocks/CU; rows 64/65 are zeroed pad read
// only by group 7's masked outputs.

#define HH 512
#define WW 512
#define OH 502           // 512 - 11 + 1
#define OW 502
#define NC 96            // 32 * 3
#define TXS 32           // strip width (output cols)
#define TYB 54           // band height (output rows)
#define INRD 64          // h-rows computed = TYB + 10; NTASK = 64*8 = 512
#define INRS 66          // stored rows (2 zero pad rows, reads masked)
#define HP4 33           // row stride in float4s (528 B -> 4-bank row rotation)
#define GX 16
#define GY 10            // 10 * 54 = 540 >= 502
#define NSLOT 64         // f64 accumulator slots, 64 B apart

typedef float f4 __attribute__((ext_vector_type(4)));

struct GaussW { float g[11]; };

static __device__ __forceinline__ f4 sp(float s) { return (f4){s, s, s, s}; }

// Issue one 16-B global load into a pinned f4; imm offset in bytes.
#define GLD(dst, p, o) \
    asm volatile("global_load_dwordx4 %0, %1, off offset:" #o \
                 : "=v"(dst) : "v"(p) : "memory")

__global__ __launch_bounds__(256, 4) void ssim_kernel(
        const float* __restrict__ X, const float* __restrict__ Y,
        double* __restrict__ acc, GaussW gw) {
    // hS[r][c] = f4(conv_h(x), conv_h(y), conv_h(x^2+y^2), conv_h(x*y)), raw
    // domain. 66*33*16 = 34848 B -> 4 blocks/CU.
    __shared__ f4 hS[INRS][HP4];
    __shared__ double wsum[4];

    const int tid = threadIdx.x;
    const int R0 = blockIdx.y * TYB;
    const int C0 = blockIdx.x * TXS;
    const float* Xp = X + (size_t)blockIdx.z * (HH * WW);
    const float* Yp = Y + (size_t)blockIdx.z * (HH * WW);
    const bool edge = (blockIdx.x == GX - 1);    // reads would pass col 511

    // zero the 2 pad rows (read by group 7, outputs masked; avoids NaN food)
    if (tid < 2 * HP4) {
        int rr = tid / HP4;
        hS[INRD + rr][tid - rr * HP4] = sp(0.f);
    }

    // h-conv one task's payload (16 x,y floats in 8 f4s) + LDS store.
    // Task map: row in LOW 3 bits -> an 8-lane phase sees 8 distinct rows ->
    // ds_write_b128 banks 4*(r+q) disjoint -> conflict-free.
    auto hconv = [&](int r, int cg, f4 X0, f4 X1, f4 X2, f4 X3,
                     f4 Y0, f4 Y1, f4 Y2, f4 Y3) {
        float xv[16], yv[16];
        #pragma unroll
        for (int i = 0; i < 4; ++i) {
            xv[i] = X0[i]; xv[4 + i] = X1[i]; xv[8 + i] = X2[i]; xv[12 + i] = X3[i];
            yv[i] = Y0[i]; yv[4 + i] = Y1[i]; yv[8 + i] = Y2[i]; yv[12 + i] = Y3[i];
        }
        f4 a0v = sp(0.f), a1v = sp(0.f), a2v = sp(0.f), a3v = sp(0.f);
        #pragma unroll
        for (int k = 0; k < 14; ++k) {
            float x = xv[k], y = yv[k];
            f4 P;
            P.x = x; P.y = y;
            P.z = fmaf(x, x, y * y);             // raw domain (sum(g)=1 lets
            P.w = x * y;                         // normalization fold into epi)
            #pragma unroll
            for (int j = 0; j < 4; ++j) {
                int u = k - j;
                if (u >= 0 && u < 11) {          // statically resolved
                    f4 G = sp(gw.g[u]);
                    if (j == 0) a0v = __builtin_elementwise_fma(G, P, a0v);
                    if (j == 1) a1v = __builtin_elementwise_fma(G, P, a1v);
                    if (j == 2) a2v = __builtin_elementwise_fma(G, P, a2v);
                    if (j == 3) a3v = __builtin_elementwise_fma(G, P, a3v);
                }
            }
        }
        hS[r][4 * cg + 0] = a0v;                 // conflict-free b128 writes
        hS[r][4 * cg + 1] = a1v;
        hS[r][4 * cg + 2] = a2v;
        hS[r][4 * cg + 3] = a3v;
    };

    // Plain-load variant for the edge strip (clamped scalar gathers).
    auto taskEdge = [&](int r, int cg) {
        const int gr = min(R0 + r, HH - 1);
        const float* xrow = Xp + gr * WW;
        const float* yrow = Yp + gr * WW;
        const int gc = C0 + 4 * cg;
        f4 xv4[4], yv4[4];
        #pragma unroll
        for (int i = 0; i < 16; ++i) {
            int c = min(gc + i, WW - 1);         // clamped cols feed masked
            xv4[i >> 2][i & 3] = xrow[c];        // outputs only (c >= 502)
            yv4[i >> 2][i & 3] = yrow[c];
        }
        hconv(r, cg, xv4[0], xv4[1], xv4[2], xv4[3],
                     yv4[0], yv4[1], yv4[2], yv4[3]);
    };

    // ---- Phase A: 512 tasks = exactly 2/thread (t0 = tid, t1 = tid + 256).
    {
        const int r0 = (tid & 7) | ((tid >> 6) << 3);
        const int g0 = (tid >> 3) & 7;
        const int t1 = tid + 256;
        const int r1 = (t1 & 7) | ((t1 >> 6) << 3);
        const int g1 = (t1 >> 3) & 7;
        if (!edge) {
            const float* px0 = Xp + min(R0 + r0, HH - 1) * WW + C0 + 4 * g0;
            const float* py0 = Yp + min(R0 + r0, HH - 1) * WW + C0 + 4 * g0;
            const float* px1 = Xp + min(R0 + r1, HH - 1) * WW + C0 + 4 * g1;
            const float* py1 = Yp + min(R0 + r1, HH - 1) * WW + C0 + 4 * g1;
            f4 xa0, xa1, xa2, xa3, ya0, ya1, ya2, ya3;
            f4 xb0, xb1, xb2, xb3, yb0, yb1, yb2, yb3;
            GLD(xa0, px0, 0); GLD(xa1, px0, 16); GLD(xa2, px0, 32); GLD(xa3, px0, 48);
            GLD(ya0, py0, 0); GLD(ya1, py0, 16); GLD(ya2, py0, 32); GLD(ya3, py0, 48);
            GLD(xb0, px1, 0); GLD(xb1, px1, 16); GLD(xb2, px1, 32); GLD(xb3, px1, 48);
            GLD(yb0, py1, 0); GLD(yb1, py1, 16); GLD(yb2, py1, 32); GLD(yb3, py1, 48);
            // t0 ready when only t1's 8 loads remain outstanding
            asm volatile("s_waitcnt vmcnt(8)"
                : "+v"(xa0), "+v"(xa1), "+v"(xa2), "+v"(xa3),
                  "+v"(ya0), "+v"(ya1), "+v"(ya2), "+v"(ya3) :: "memory");
            hconv(r0, g0, xa0, xa1, xa2, xa3, ya0, ya1, ya2, ya3);
            asm volatile("s_waitcnt vmcnt(0)"
                : "+v"(xb0), "+v"(xb1), "+v"(xb2), "+v"(xb3),
                  "+v"(yb0), "+v"(yb1), "+v"(yb2), "+v"(yb3) :: "memory");
            hconv(r1, g1, xb0, xb1, xb2, xb3, yb0, yb1, yb2, yb3);
        } else {
            taskEdge(r0, g0);
            taskEdge(r1, g1);
        }
    }
    __syncthreads();

    // ---- Phase B: vertical 11-tap conv + SSIM. 8 col-groups x 7 rows each
    // (56 >= 54; rows 54/55 masked). Read: 8-lane phase shares a row, cols
    // 0..7(+8m) -> banks 4(R+c) disjoint -> conflict-free.
    const int c  = tid & 31;
    const int rb = 7 * (tid >> 5);               // 0,7,...,49
    f4 A[7];
    #pragma unroll
    for (int j = 0; j < 7; ++j) A[j] = sp(0.f);
    #pragma unroll
    for (int k = 0; k < 17; ++k) {               // rows rb..rb+16 feed rb..rb+6
        f4 v = hS[rb + k][c];                    // one ds_read_b128 per tap-row
        #pragma unroll
        for (int j = 0; j < 7; ++j) {
            int u = k - j;
            if (u >= 0 && u < 11) {
                f4 G = sp(gw.g[u]);
                A[j] = __builtin_elementwise_fma(G, v, A[j]);
            }
        }
    }

    // Epilogue: raw-domain fixup. With u=(x+1)/2: 2*mu = cx+1,
    // sigma1^2+sigma2^2 = (cs - cx^2 - cy^2)/4, sigma12 = (cp - cx*cy)/4.
    const float C1 = 1.0e-4f;
    const float C2 = 9.0e-4f;
    float nn[7], dd[7];
    #pragma unroll
    for (int j = 0; j < 7; ++j) {
        f4 v = A[j];
        float t1 = v.x + 1.f, t2 = v.y + 1.f;    // 2*mu1, 2*mu2
        float num1 = fmaf(t1 * t2, 0.5f, C1);    // 2*mu1*mu2 + C1
        float den1 = fmaf(fmaf(t2, t2, t1 * t1), 0.25f, C1);
        float num2 = fmaf(v.w - v.x * v.y, 0.5f, C2);   // 2*sigma12 + C2
        float den2 = fmaf(v.z - fmaf(v.x, v.x, v.y * v.y), 0.25f, C2);
        bool valid = (rb + j < TYB) & (R0 + rb + j < OH) & (C0 + c < OW);
        nn[j] = valid ? num1 * num2 : 0.f;
        dd[j] = valid ? den1 * den2 : 1.f;
    }
    // 2 divides for 7 outputs: common denominator per group (4 + 3)
    // (dd >= C1*C2 ~ 1e-7; 4-products >= ~6e-29 stay normal in f32)
    double tsum = 0.0;
    {
        float d01 = dd[0] * dd[1], d23 = dd[2] * dd[3];
        float s01 = fmaf(nn[0], dd[1], nn[1] * dd[0]);
        float s23 = fmaf(nn[2], dd[3], nn[3] * dd[2]);
        tsum += (double)(fmaf(s01, d23, s23 * d01) / (d01 * d23));
        float d45 = dd[4] * dd[5];
        float s45 = fmaf(nn[4], dd[5], nn[5] * dd[4]);
        float num = fmaf(s45, dd[6], nn[6] * d45);
        tsum += (double)(num / (d45 * dd[6]));
    }

    // block reduction (double) + one f64 atomic into a strided slot
    #pragma unroll
    for (int off = 32; off > 0; off >>= 1)
        tsum += __shfl_down(tsum, off, 64);
    if ((tid & 63) == 0) wsum[tid >> 6] = tsum;
    __syncthreads();
    if (tid == 0) {
        int slot = (blockIdx.x + blockIdx.y * GX + blockIdx.z * GX * GY) & (NSLOT - 1);
        atomicAdd(&acc[slot * 8], wsum[0] + wsum[1] + wsum[2] + wsum[3]);
    }
}

__global__ void ssim_finalize(const double* __restrict__ acc,
                              float* __restrict__ out) {
    int lane = threadIdx.x;                      // 64 threads, one slot each
    double t = acc[lane * 8];
    #pragma unroll
    for (int off = 32; off > 0; off >>= 1)
        t += __shfl_down(t, off, 64);
    if (lane == 0)
        out[0] = (float)(t * (1.0 / (double)((long long)NC * OH * OW)));
}

extern "C" void kernel_launch(void* const* d_in, const int* in_sizes, int n_in,
                              void* d_out, int out_size, void* d_ws, size_t ws_size,
                              hipStream_t stream) {
    const float* X = (const float*)d_in[0];
    const float* Y = (const float*)d_in[1];
    float* out = (float*)d_out;
    double* acc = (double*)d_ws;                 // 64 slots x 64 B = 4 KB

    // d_ws is re-poisoned to 0xAA before every timed launch: zero the slots.
    hipMemsetAsync(d_ws, 0, NSLOT * 64, stream);

    // Gaussian weights (win=11, sigma=1.5), computed in f64, passed by value.
    GaussW gw;
    {
        double g[11], s = 0.0;
        for (int i = 0; i < 11; ++i) {
            double d = (double)(i - 5);
            g[i] = exp(-d * d / (2.0 * 1.5 * 1.5));
            s += g[i];
        }
        for (int i = 0; i < 11; ++i) gw.g[i] = (float)(g[i] / s);
    }

    dim3 grid(GX, GY, NC);
    ssim_kernel<<<grid, dim3(256), 0, stream>>>(X, Y, acc, gw);
    ssim_finalize<<<1, dim3(64), 0, stream>>>(acc, out);
}

// Round 6
// 261.698 us; speedup vs baseline: 1.2727x; 1.2617x over previous
//
#include <hip/hip_runtime.h>
#include <cmath>

// SSIM over (32,3,512,512) f32 pairs, 11x11 separable gaussian, valid conv,
// scalar mean output. Round 11 = Round 10 resubmit (container infra failure,
// no dispatch record; kernel re-audited: DMA alignment, wave-uniform LDS
// base, OOB, NaN paths all clean). Structure: Phase A staged via
// __builtin_amdgcn_global_load_lds bulk DMA. R5-R9 showed the per-task
// load->VGPR->compute structure is latency-convoyed at ~43% VALUBusy and
// immune to ILP pinning (R6/R7/R9) and TLP (R8). Raw x,y rows are DMA'd
// lane-linear into LDS (one 16.6 KB burst per block, ~4x less global issue
// than the redundant 16-cols-per-4-outputs register loads), drained by the
// single vmcnt(0) the compiler emits at __syncthreads, then h-conv reads LDS
// (short, hideable latency) and Phase B is unchanged. Geometry TYB=30/INR=40:
// 320 tasks = 256+64 keeps the bit-swapped conflict-free map exact; raw
// stride 13 f4 (odd) makes task reads 2-way-max (free); hS gets 2 pad rows
// (garbage-read, consumers masked). LDS 38.8 KB -> 4 blocks/CU.

#define HH 512
#define WW 512
#define OH 502           // 512 - 11 + 1
#define OW 502
#define NC 96            // 32 * 3
#define TXS 32           // strip width (output cols)
#define TYB 30           // band height (output rows)
#define INR 40           // h-rows computed = TYB + 10; tasks = 40*8 = 320
#define INRS 42          // hS rows allocated (rows 40,41 garbage-read, masked)
#define RAWP 13          // raw row stride in f4s (odd -> conflict-free reads)
#define NRAW (INR*RAWP)  // 520 f4 slots per array (x then y)
#define HP4 33           // hS row stride in float4s (528 B)
#define GX 16
#define GY 17            // 17 * 30 = 510 >= 502
#define NSLOT 64         // f64 accumulator slots, 64 B apart

typedef float f4 __attribute__((ext_vector_type(4)));

struct GaussW { float g[11]; };

static __device__ __forceinline__ f4 sp(float s) { return (f4){s, s, s, s}; }

__global__ __launch_bounds__(256, 4) void ssim_kernel(
        const float* __restrict__ X, const float* __restrict__ Y,
        double* __restrict__ acc, GaussW gw) {
    // rawS: [0..519] x-rows, [520..1039] y-rows; slot i = 13*r + c4,
    // c4 0..11 real (cols C0+4*c4..+3, clamped at image edge), c4 12 dead.
    // hS[r][c] = f4(conv_h(x), conv_h(y), conv_h(x^2+y^2), conv_h(x*y)).
    __shared__ f4 rawS[2 * NRAW];                // 16640 B
    __shared__ f4 hS[INRS][HP4];                 // 22176 B
    __shared__ double wsum[4];

    const int tid = threadIdx.x;
    const int R0 = blockIdx.y * TYB;
    const int C0 = blockIdx.x * TXS;
    const float* Xp = X + (size_t)blockIdx.z * (HH * WW);
    const float* Yp = Y + (size_t)blockIdx.z * (HH * WW);

    // ---- Phase A-stage: async DMA, lane-linear. 1040 slots / 256 threads =
    // 5 rounds (last partial: 16 lanes of wave 0). LDS dest is wave-uniform
    // base + lane*16 (HW rule), so dst = &rawS[i & ~63]; global src is
    // per-lane, so the edge-column clamp folds into the address (min).
    #pragma unroll
    for (int k = 0; k < 5; ++k) {
        int i = (k << 8) + tid;
        if (i < 2 * NRAW) {
            int a  = i >= NRAW;                  // 0 = X, 1 = Y
            int j  = a ? i - NRAW : i;
            int r  = j / RAWP;                   // magic-mul division
            int c4 = j - r * RAWP;
            const float* bp  = a ? Yp : Xp;
            const float* src = bp + min(R0 + r, HH - 1) * WW
                                  + min(C0 + 4 * c4, WW - 4);
            f4* dst = &rawS[i & ~63];            // wave-uniform base
            __builtin_amdgcn_global_load_lds(
                (const __attribute__((address_space(1))) void*)src,
                (__attribute__((address_space(3))) void*)dst, 16, 0, 0);
        }
    }
    __syncthreads();                             // one vmcnt(0) drain/block

    // ---- Phase A-compute: h-conv one task (4 h-cols) from rawS, write hS.
    // Task map keeps row in LOW 3 bits: a 16-lane phase sees 8 distinct rows
    // x 2 cgs -> raw-read quads (5r+cg+t)&7 and hS-write quads (r+4cg+q)&7
    // each hit exactly 2x -> conflict-free (2-way is free, m136).
    auto task = [&](int r, int cg) {
        const int ib = RAWP * r + cg;
        f4 x0 = rawS[ib + 0], x1 = rawS[ib + 1];
        f4 x2 = rawS[ib + 2], x3 = rawS[ib + 3];
        f4 y0 = rawS[NRAW + ib + 0], y1 = rawS[NRAW + ib + 1];
        f4 y2 = rawS[NRAW + ib + 2], y3 = rawS[NRAW + ib + 3];
        float xv[16], yv[16];
        #pragma unroll
        for (int i = 0; i < 4; ++i) {
            xv[i] = x0[i]; xv[4 + i] = x1[i]; xv[8 + i] = x2[i]; xv[12 + i] = x3[i];
            yv[i] = y0[i]; yv[4 + i] = y1[i]; yv[8 + i] = y2[i]; yv[12 + i] = y3[i];
        }
        f4 a0v = sp(0.f), a1v = sp(0.f), a2v = sp(0.f), a3v = sp(0.f);
        #pragma unroll
        for (int k = 0; k < 14; ++k) {
            float x = xv[k], y = yv[k];
            f4 P;
            P.x = x; P.y = y;
            P.z = fmaf(x, x, y * y);             // raw domain (sum(g)=1 lets
            P.w = x * y;                         // normalization fold into epi)
            #pragma unroll
            for (int j = 0; j < 4; ++j) {
                int u = k - j;
                if (u >= 0 && u < 11) {          // statically resolved
                    f4 G = sp(gw.g[u]);
                    if (j == 0) a0v = __builtin_elementwise_fma(G, P, a0v);
                    if (j == 1) a1v = __builtin_elementwise_fma(G, P, a1v);
                    if (j == 2) a2v = __builtin_elementwise_fma(G, P, a2v);
                    if (j == 3) a3v = __builtin_elementwise_fma(G, P, a3v);
                }
            }
        }
        hS[r][4 * cg + 0] = a0v;                 // conflict-free b128 writes
        hS[r][4 * cg + 1] = a1v;
        hS[r][4 * cg + 2] = a2v;
        hS[r][4 * cg + 3] = a3v;
    };
    {
        const int cg = (tid >> 3) & 7;
        task((tid & 7) | ((tid >> 6) << 3), cg); // rows 0..31
        if (tid < 64) task((tid & 7) | 32, cg);  // rows 32..39 (tail batch)
    }
    __syncthreads();

    // ---- Phase B: vertical 11-tap conv + SSIM. 8 col-groups x 4 rows each
    // (32 >= 30; rows 30,31 masked). 16-lane phase shares a row, 16 cols ->
    // quads (R+c)&7 hit 2x -> free. Reads reach hS rows rb..rb+13 <= 41.
    const int c  = tid & 31;
    const int rb = (tid >> 5) * 4;               // 0,4,...,28
    f4 A[4];
    #pragma unroll
    for (int j = 0; j < 4; ++j) A[j] = sp(0.f);
    #pragma unroll
    for (int k = 0; k < 14; ++k) {               // rows rb..rb+13 feed rb..rb+3
        f4 v = hS[rb + k][c];                    // one ds_read_b128 per tap-row
        #pragma unroll
        for (int j = 0; j < 4; ++j) {
            int u = k - j;
            if (u >= 0 && u < 11) {
                f4 G = sp(gw.g[u]);
                A[j] = __builtin_elementwise_fma(G, v, A[j]);
            }
        }
    }

    // Epilogue: raw-domain fixup. With u=(x+1)/2: 2*mu = cx+1,
    // sigma1^2+sigma2^2 = (cs - cx^2 - cy^2)/4, sigma12 = (cp - cx*cy)/4.
    const float C1 = 1.0e-4f;
    const float C2 = 9.0e-4f;
    float nn[4], dd[4];
    #pragma unroll
    for (int j = 0; j < 4; ++j) {
        f4 v = A[j];
        float t1 = v.x + 1.f, t2 = v.y + 1.f;    // 2*mu1, 2*mu2
        float num1 = fmaf(t1 * t2, 0.5f, C1);    // 2*mu1*mu2 + C1
        float den1 = fmaf(fmaf(t2, t2, t1 * t1), 0.25f, C1);
        float num2 = fmaf(v.w - v.x * v.y, 0.5f, C2);   // 2*sigma12 + C2
        float den2 = fmaf(v.z - fmaf(v.x, v.x, v.y * v.y), 0.25f, C2);
        bool valid = (rb + j < TYB) & (R0 + rb + j < OH) & (C0 + c < OW);
        nn[j] = valid ? num1 * num2 : 0.f;       // garbage/NaN rows land here
        dd[j] = valid ? den1 * den2 : 1.f;       // and are replaced -> safe
    }
    // 1 divide for 4 outputs: common denominator
    // (dd >= C1*C2 ~ 1e-7; 4-products >= ~6e-29 stay normal in f32)
    float d01 = dd[0] * dd[1], d23 = dd[2] * dd[3];
    float s01 = fmaf(nn[0], dd[1], nn[1] * dd[0]);
    float s23 = fmaf(nn[2], dd[3], nn[3] * dd[2]);
    double tsum = (double)(fmaf(s01, d23, s23 * d01) / (d01 * d23));

    // block reduction (double) + one f64 atomic into a strided slot
    #pragma unroll
    for (int off = 32; off > 0; off >>= 1)
        tsum += __shfl_down(tsum, off, 64);
    if ((tid & 63) == 0) wsum[tid >> 6] = tsum;
    __syncthreads();
    if (tid == 0) {
        int slot = (blockIdx.x + blockIdx.y * GX + blockIdx.z * GX * GY) & (NSLOT - 1);
        atomicAdd(&acc[slot * 8], wsum[0] + wsum[1] + wsum[2] + wsum[3]);
    }
}

__global__ void ssim_finalize(const double* __restrict__ acc,
                              float* __restrict__ out) {
    int lane = threadIdx.x;                      // 64 threads, one slot each
    double t = acc[lane * 8];
    #pragma unroll
    for (int off = 32; off > 0; off >>= 1)
        t += __shfl_down(t, off, 64);
    if (lane == 0)
        out[0] = (float)(t * (1.0 / (double)((long long)NC * OH * OW)));
}

extern "C" void kernel_launch(void* const* d_in, const int* in_sizes, int n_in,
                              void* d_out, int out_size, void* d_ws, size_t ws_size,
                              hipStream_t stream) {
    const float* X = (const float*)d_in[0];
    const float* Y = (const float*)d_in[1];
    float* out = (float*)d_out;
    double* acc = (double*)d_ws;                 // 64 slots x 64 B = 4 KB

    // d_ws is re-poisoned to 0xAA before every timed launch: zero the slots.
    hipMemsetAsync(d_ws, 0, NSLOT * 64, stream);

    // Gaussian weights (win=11, sigma=1.5), computed in f64, passed by value.
    GaussW gw;
    {
        double g[11], s = 0.0;
        for (int i = 0; i < 11; ++i) {
            double d = (double)(i - 5);
            g[i] = exp(-d * d / (2.0 * 1.5 * 1.5));
            s += g[i];
        }
        for (int i = 0; i < 11; ++i) gw.g[i] = (float)(g[i] / s);
    }

    dim3 grid(GX, GY, NC);
    ssim_kernel<<<grid, dim3(256), 0, stream>>>(X, Y, acc, gw);
    ssim_finalize<<<1, dim3(64), 0, stream>>>(acc, out);
}

// Round 7
// 252.386 us; speedup vs baseline: 1.3197x; 1.0369x over previous
//
#include <hip/hip_runtime.h>
#include <cmath>

// SSIM over (32,3,512,512) f32 pairs, 11x11 separable gaussian, valid conv,
// scalar mean output. Round 12: persistent column-strip blocks. R10 (DMA
// staging) was the first structural win (162->141us, VALUBusy 43->69%);
// VALU-issue now dominates (~97us busy of 141). Remaining waste: 1.33x
// h-conv halo recompute across 30-row bands + a cold DMA drain per band
// block. This kernel gives each block a 32-col x 512-row strip (grid 16x96
// = 1536 blocks), looping 16 iterations of 32 output rows with ring buffers:
//   raw ring: 64 rows x 13 f4 x {X,Y} (26.6 KB) - each image row DMA'd ONCE;
//     slot(row) = (row+22)%64 makes every 32-row DMA batch land in one
//     contiguous 32-row half (no mid-wave wrap -> wave-linear dst).
//   hS ring: 48 rows x 33 f4 (25.3 KB) - each h-row convolved ONCE (was 1.33x).
// Pipeline per iter i: issue DMA batch i (rows 32i+42..+73, consumed next
// iter) | h-conv 32 rows | lgkmcnt(0); s_barrier | v-conv 32 rows + SSIM |
// vmcnt(0) lgkmcnt(0); s_barrier. The mid barrier does NOT drain vmcnt
// (m201 counted-vmcnt pattern), so DMA latency hides under a full iteration
// (~2400cy >> ~900cy HBM). Iter 0 special: 42-row h-conv warmup, DMA 0
// issued after the mid barrier (slot overlap with warmup reads otherwise).
// All bank-conflict-free maps survive (ring sizes are multiples of 8 rows).
// LDS 52 KB -> 3 blocks/CU.

#define HH 512
#define WW 512
#define OH 502           // 512 - 11 + 1
#define OW 502
#define NC 96            // 32 * 3
#define TXS 32           // strip width (output cols)
#define BROWS 32         // output rows per iteration
#define NIT 16           // 16 * 32 = 512 rows
#define RAWR 64          // raw ring rows (two 32-row halves)
#define RAWP 13          // raw row stride in f4s (odd -> conflict-free reads)
#define HSR 48           // hS ring rows (>= 42 live, multiple of 8)
#define HP4 33           // hS row stride in f4s (528 B -> 4-bank row rotation)
#define GX 16
#define NSLOT 64         // f64 accumulator slots, 64 B apart

typedef float f4 __attribute__((ext_vector_type(4)));

struct GaussW { float g[11]; };

static __device__ __forceinline__ f4 sp(float s) { return (f4){s, s, s, s}; }

#define FENCE() asm volatile("" ::: "memory")

__global__ __launch_bounds__(256, 4) void ssim_kernel(
        const float* __restrict__ X, const float* __restrict__ Y,
        double* __restrict__ acc, GaussW gw) {
    // rawS: [a][rslot][c4] flat; slot(row) = (row+22) % 64; c4 0..10 real,
    // 11..12 clamped-garbage (never read; keep stride 13 for banking +
    // wave-linear DMA). hS[s][c]: s = row % 48, 4-channel h-conv rows.
    __shared__ f4 rawS[2 * RAWR * RAWP];         // 26624 B
    __shared__ f4 hS[HSR][HP4];                  // 25344 B
    __shared__ double wsum[4];

    const int tid = threadIdx.x;
    const int C0 = blockIdx.x * TXS;
    const float* Xp = X + (size_t)blockIdx.y * (HH * WW);
    const float* Yp = Y + (size_t)blockIdx.y * (HH * WW);

    // One DMA slot: row/col clamped per-lane in the SRC address (edge strip
    // and bottom tail read duplicated data -> finite, consumers masked).
    auto dma1 = [&](int a, int slot_f4, int row, int c4) {
        const float* bp  = a ? Yp : Xp;
        const float* src = bp + (size_t)min(row, HH - 1) * WW
                              + min(C0 + 4 * c4, WW - 4);
        f4* dst = rawS + a * (RAWR * RAWP) + slot_f4;  // wave-uniform base
        __builtin_amdgcn_global_load_lds(
            (const __attribute__((address_space(1))) void*)src,
            (__attribute__((address_space(3))) void*)dst, 16, 0, 0);
    };

    // DMA batch i: rows [32i+42, 32i+74) -> raw half (i&1) (f4 base (i&1)*416).
    // slot = (i&1)*416 + idx, linear in idx -> wave-uniform dst base + lane*16.
    auto dma_batch = [&](int i) {
        const int half = (i & 1) * (BROWS * RAWP);   // 0 or 416
        const int br = 32 * i + 42;
        #pragma unroll
        for (int a = 0; a < 2; ++a)
            #pragma unroll
            for (int k = 0; k < 2; ++k) {
                int idx = (k << 8) + tid;
                if (idx < BROWS * RAWP) {            // 416; round 1: tid<160
                    int o = idx / 13, c4 = idx - o * 13;
                    dma1(a, half + (k << 8) + (tid & ~63), br + o, c4);
                }
            }
    };

    // h-conv one task (4 output cols) from raw ring, write hS ring.
    // Task map keeps row in LOW 3 bits -> 8-lane phases see 8 distinct rows:
    // raw-read quads (5(rbm+o)+cg)&7 and hS-write quads (hs+4cg+q)&7 are
    // 2-way max (free, m136) since ring sizes are multiples of 8.
    auto htask = [&](int o, int cg, int rbm, int bm) {
        const int rs = rbm + o;                  // never wraps (by schedule)
        int hs = bm + o; if (hs >= HSR) hs -= HSR;
        const int ib = rs * RAWP + cg;
        f4 x0 = rawS[ib + 0], x1 = rawS[ib + 1];
        f4 x2 = rawS[ib + 2], x3 = rawS[ib + 3];
        f4 y0 = rawS[RAWR * RAWP + ib + 0], y1 = rawS[RAWR * RAWP + ib + 1];
        f4 y2 = rawS[RAWR * RAWP + ib + 2], y3 = rawS[RAWR * RAWP + ib + 3];
        float xv[16], yv[16];
        #pragma unroll
        for (int q = 0; q < 4; ++q) {
            xv[q] = x0[q]; xv[4 + q] = x1[q]; xv[8 + q] = x2[q]; xv[12 + q] = x3[q];
            yv[q] = y0[q]; yv[4 + q] = y1[q]; yv[8 + q] = y2[q]; yv[12 + q] = y3[q];
        }
        f4 a0v = sp(0.f), a1v = sp(0.f), a2v = sp(0.f), a3v = sp(0.f);
        #pragma unroll
        for (int k = 0; k < 14; ++k) {
            float x = xv[k], y = yv[k];
            f4 P;
            P.x = x; P.y = y;
            P.z = fmaf(x, x, y * y);             // raw domain (sum(g)=1 lets
            P.w = x * y;                         // normalization fold into epi)
            #pragma unroll
            for (int j = 0; j < 4; ++j) {
                int u = k - j;
                if (u >= 0 && u < 11) {          // statically resolved
                    f4 G = sp(gw.g[u]);
                    if (j == 0) a0v = __builtin_elementwise_fma(G, P, a0v);
                    if (j == 1) a1v = __builtin_elementwise_fma(G, P, a1v);
                    if (j == 2) a2v = __builtin_elementwise_fma(G, P, a2v);
                    if (j == 3) a3v = __builtin_elementwise_fma(G, P, a3v);
                }
            }
        }
        hS[hs][4 * cg + 0] = a0v;                // conflict-free b128 writes
        hS[hs][4 * cg + 1] = a1v;
        hS[hs][4 * cg + 2] = a2v;
        hS[hs][4 * cg + 3] = a3v;
    };

    // ---- warmup: stage rows [0,42) -> raw slots 286+idx (rslots 22..63)
    #pragma unroll
    for (int a = 0; a < 2; ++a)
        #pragma unroll
        for (int k = 0; k < 3; ++k) {
            int idx = (k << 8) + tid;
            if (idx < 42 * RAWP) {               // 546; round 2: tid<34
                int o = idx / 13, c4 = idx - o * 13;
                dma1(a, 22 * RAWP + (k << 8) + (tid & ~63), o, c4);
            }
        }
    asm volatile("s_waitcnt vmcnt(0)" ::: "memory");
    __builtin_amdgcn_s_barrier();
    FENCE();

    // ---- main loop: 16 iterations of 32 output rows
    double tsum = 0.0;
    const int c  = tid & 31;
    const int rb = (tid >> 5) * 4;               // 0,4,...,28
    int bm = 0;                                  // h-write base: (32i+10)%48 (0 @ i=0)
    int vb = 0;                                  // v-read base: (32i)%48

    for (int i = 0; i < NIT; ++i) {
        if (i >= 1 && i <= 14) dma_batch(i);     // prefetch next iter's rows

        // h-conv: iter 0 = rows [0,42) (336 tasks); else rows [32i+10,+42).
        const int rbm = (i == 0) ? 22 : (((i + 1) & 1) << 5);
        {
            const int cg = (tid >> 3) & 7;
            const int o  = (tid & 7) | ((tid >> 6) << 3);
            htask(o, cg, rbm, bm);
            if (i == 0) {
                if (tid < 64) htask(32 + (tid & 7), (tid >> 3) & 7, rbm, bm);
                if (tid < 16) htask(40 + (tid & 1), (tid >> 1) & 7, rbm, bm);
            }
        }
        asm volatile("s_waitcnt lgkmcnt(0)" ::: "memory");  // publish hS
        __builtin_amdgcn_s_barrier();            // NO vmcnt drain here
        FENCE();
        if (i == 0) dma_batch(0);                // slots clash with warmup reads
                                                 // -> must issue post-barrier
        // v-conv + SSIM epilogue: 1 col x 4 rows per thread.
        f4 A[4];
        #pragma unroll
        for (int j = 0; j < 4; ++j) A[j] = sp(0.f);
        #pragma unroll
        for (int k = 0; k < 14; ++k) {
            int s = vb + rb + k; if (s >= HSR) s -= HSR;
            f4 v = hS[s][c];                     // one ds_read_b128 per tap-row
            #pragma unroll
            for (int j = 0; j < 4; ++j) {
                int u = k - j;
                if (u >= 0 && u < 11) {
                    f4 G = sp(gw.g[u]);
                    A[j] = __builtin_elementwise_fma(G, v, A[j]);
                }
            }
        }
        const float C1 = 1.0e-4f;
        const float C2 = 9.0e-4f;
        float nn[4], dd[4];
        #pragma unroll
        for (int j = 0; j < 4; ++j) {
            f4 v = A[j];
            float t1 = v.x + 1.f, t2 = v.y + 1.f;        // 2*mu1, 2*mu2
            float num1 = fmaf(t1 * t2, 0.5f, C1);        // 2*mu1*mu2 + C1
            float den1 = fmaf(fmaf(t2, t2, t1 * t1), 0.25f, C1);
            float num2 = fmaf(v.w - v.x * v.y, 0.5f, C2);       // 2*sig12 + C2
            float den2 = fmaf(v.z - fmaf(v.x, v.x, v.y * v.y), 0.25f, C2);
            bool valid = (32 * i + rb + j < OH) & (C0 + c < OW);
            nn[j] = valid ? num1 * num2 : 0.f;   // clamped-junk rows land here
            dd[j] = valid ? den1 * den2 : 1.f;   // and are replaced -> safe
        }
        // 1 divide / 4 outputs via common denominator
        // (dd >= C1*C2 ~ 1e-7; 4-products >= ~6e-29 stay normal in f32)
        float d01 = dd[0] * dd[1], d23 = dd[2] * dd[3];
        float s01 = fmaf(nn[0], dd[1], nn[1] * dd[0]);
        float s23 = fmaf(nn[2], dd[3], nn[3] * dd[2]);
        tsum += (double)(fmaf(s01, d23, s23 * d01) / (d01 * d23));

        // end-of-iter: drain this iter's DMA (issued ~1 iter ago -> cheap),
        // and protect hS/raw rings before next iter overwrites.
        asm volatile("s_waitcnt vmcnt(0) lgkmcnt(0)" ::: "memory");
        __builtin_amdgcn_s_barrier();
        FENCE();

        bm = (i == 0) ? 42 : (bm + 32 >= HSR ? bm + 32 - HSR : bm + 32);
        vb = (vb + 32 >= HSR) ? vb + 32 - HSR : vb + 32;
    }

    // block reduction (double) + one f64 atomic into a strided slot
    #pragma unroll
    for (int off = 32; off > 0; off >>= 1)
        tsum += __shfl_down(tsum, off, 64);
    if ((tid & 63) == 0) wsum[tid >> 6] = tsum;
    __syncthreads();
    if (tid == 0) {
        int slot = (blockIdx.x + blockIdx.y * GX) & (NSLOT - 1);
        atomicAdd(&acc[slot * 8], wsum[0] + wsum[1] + wsum[2] + wsum[3]);
    }
}

__global__ void ssim_finalize(const double* __restrict__ acc,
                              float* __restrict__ out) {
    int lane = threadIdx.x;                      // 64 threads, one slot each
    double t = acc[lane * 8];
    #pragma unroll
    for (int off = 32; off > 0; off >>= 1)
        t += __shfl_down(t, off, 64);
    if (lane == 0)
        out[0] = (float)(t * (1.0 / (double)((long long)NC * OH * OW)));
}

extern "C" void kernel_launch(void* const* d_in, const int* in_sizes, int n_in,
                              void* d_out, int out_size, void* d_ws, size_t ws_size,
                              hipStream_t stream) {
    const float* X = (const float*)d_in[0];
    const float* Y = (const float*)d_in[1];
    float* out = (float*)d_out;
    double* acc = (double*)d_ws;                 // 64 slots x 64 B = 4 KB

    // d_ws is re-poisoned to 0xAA before every timed launch: zero the slots.
    hipMemsetAsync(d_ws, 0, NSLOT * 64, stream);

    // Gaussian weights (win=11, sigma=1.5), computed in f64, passed by value.
    GaussW gw;
    {
        double g[11], s = 0.0;
        for (int i = 0; i < 11; ++i) {
            double d = (double)(i - 5);
            g[i] = exp(-d * d / (2.0 * 1.5 * 1.5));
            s += g[i];
        }
        for (int i = 0; i < 11; ++i) gw.g[i] = (float)(g[i] / s);
    }

    dim3 grid(GX, NC);
    ssim_kernel<<<grid, dim3(256), 0, stream>>>(X, Y, acc, gw);
    ssim_finalize<<<1, dim3(64), 0, stream>>>(acc, out);
}

// Round 8
// 243.356 us; speedup vs baseline: 1.3687x; 1.0371x over previous
//
#include <hip/hip_runtime.h>
#include <cmath>

// SSIM over (32,3,512,512) f32 pairs, 11x11 separable gaussian, valid conv,
// scalar mean output. Round 13: R12's persistent-strip ring kernel, LDS diet
// 52.2 -> 39.2 KB to restore 4 blocks/CU (R12 measured VALUBusy 57% at 3
// blocks vs R10's 69% at 4 -> idle is fillable by neighbor blocks):
//   - RAWP 13->11 f4 (42 cols live; 11 odd keeps (3rs+cg)&7 rotation
//     conflict-free; -15% DMA instructions)
//   - raw ring 64->48 rows: DMA batch split A/B 16-row halves. A issued
//     pre-h-conv (hides under h+v), B post-mid-barrier (hides under v);
//     ring holds 3 rotating 16-row thirds, all liveness cases checked.
//   - hS ring 48->44 rows (live window 42; wrap shifts residues by 4 mod 8
//     -> worst 2-way write phases = free, m136)
// 4 blocks/CU x 1536 blocks = 1.5 residency rounds -> 25% tail; fixed by
// half-strips: grid 16x2x96 = 3072 = 3 clean rounds (+2% warmup work).
// Everything else (task maps, counted-vmcnt barriers, epilogue) = R12.

#define HH 512
#define WW 512
#define OH 502           // 512 - 11 + 1
#define OW 502
#define NC 96            // 32 * 3
#define TXS 32           // strip width (output cols)
#define BROWS 32         // output rows per iteration
#define NIT 8            // 8 * 32 = 256 rows per half-strip
#define RAWR 48          // raw ring rows (three 16-row thirds)
#define RAWP 11          // raw row stride in f4s (odd -> conflict-free reads)
#define HSR 44           // hS ring rows (42 live; mod-44 wrap <= 2-way = free)
#define HP4 33           // hS row stride in f4s (528 B -> 4-bank row rotation)
#define GX 16
#define NSLOT 64         // f64 accumulator slots, 64 B apart

typedef float f4 __attribute__((ext_vector_type(4)));

struct GaussW { float g[11]; };

static __device__ __forceinline__ f4 sp(float s) { return (f4){s, s, s, s}; }

#define FENCE() asm volatile("" ::: "memory")

__global__ __launch_bounds__(256, 4) void ssim_kernel(
        const float* __restrict__ X, const float* __restrict__ Y,
        double* __restrict__ acc, GaussW gw) {
    // rawS: [a][rslot][c4] flat, slot(local row) = (row+6) % 48; 11 f4/row
    // (44 cols; cols 42,43 loaded-unused). hS[s][c]: s = row % 44.
    __shared__ f4 rawS[2 * RAWR * RAWP];         // 16896 B
    __shared__ f4 hS[HSR][HP4];                  // 23232 B
    __shared__ double wsum[4];                   // total 40160 B -> 4 blk/CU

    const int tid = threadIdx.x;
    const int C0 = blockIdx.x * TXS;
    const int R0 = blockIdx.y * (BROWS * NIT);   // 0 or 256 (half-strip)
    const float* Xp = X + (size_t)blockIdx.z * (HH * WW);
    const float* Yp = Y + (size_t)blockIdx.z * (HH * WW);

    // One DMA slot: row/col clamped per-lane in the SRC address (edge strip
    // and bottom tail read duplicated data -> finite, consumers masked).
    auto dma1 = [&](int a, int slot_f4, int grow, int c4) {
        const float* bp  = a ? Yp : Xp;
        const float* src = bp + (size_t)min(grow, HH - 1) * WW
                              + min(C0 + 4 * c4, WW - 4);
        f4* dst = rawS + a * (RAWR * RAWP) + slot_f4;  // wave-uniform base
        __builtin_amdgcn_global_load_lds(
            (const __attribute__((address_space(1))) void*)src,
            (__attribute__((address_space(3))) void*)dst, 16, 0, 0);
    };

    // 16-row DMA half-batch: h=0 -> local rows 32i+42.., h=1 -> 32i+58..
    // Target third base tb = ((br+6)%48)*11; idx linear in tid -> dst is
    // wave-uniform base + lane*16 (HW requirement).
    auto dma_half = [&](int i, int h) {
        const int br = 32 * i + 42 + 16 * h;
        const int tb = ((br + 6) % RAWR) * RAWP; // 0 / 176 / 352
        if (tid < 16 * RAWP) {                   // 176
            int o = tid / RAWP, c4 = tid - o * RAWP;
            int db = tb + (tid & ~63);
            dma1(0, db, R0 + br + o, c4);
            dma1(1, db, R0 + br + o, c4);
        }
    };

    // h-conv one task (4 output cols) from raw ring, write hS ring.
    // Task map keeps row in LOW 3 bits; ring wraps preserve the residue
    // maps: raw (3rs+cg)&7 distinct (48=0 mod 8), hS <=2-way (44=4 mod 8).
    auto htask = [&](int o, int cg, int rbm, int bm) {
        int rs = rbm + o; if (rs >= RAWR) rs -= RAWR;
        int hs = bm + o;  if (hs >= HSR)  hs -= HSR;
        const int ib = rs * RAWP + cg;
        f4 x0 = rawS[ib + 0], x1 = rawS[ib + 1];
        f4 x2 = rawS[ib + 2], x3 = rawS[ib + 3];
        f4 y0 = rawS[RAWR * RAWP + ib + 0], y1 = rawS[RAWR * RAWP + ib + 1];
        f4 y2 = rawS[RAWR * RAWP + ib + 2], y3 = rawS[RAWR * RAWP + ib + 3];
        float xv[16], yv[16];
        #pragma unroll
        for (int q = 0; q < 4; ++q) {
            xv[q] = x0[q]; xv[4 + q] = x1[q]; xv[8 + q] = x2[q]; xv[12 + q] = x3[q];
            yv[q] = y0[q]; yv[4 + q] = y1[q]; yv[8 + q] = y2[q]; yv[12 + q] = y3[q];
        }
        f4 a0v = sp(0.f), a1v = sp(0.f), a2v = sp(0.f), a3v = sp(0.f);
        #pragma unroll
        for (int k = 0; k < 14; ++k) {
            float x = xv[k], y = yv[k];
            f4 P;
            P.x = x; P.y = y;
            P.z = fmaf(x, x, y * y);             // raw domain (sum(g)=1 lets
            P.w = x * y;                         // normalization fold into epi)
            #pragma unroll
            for (int j = 0; j < 4; ++j) {
                int u = k - j;
                if (u >= 0 && u < 11) {          // statically resolved
                    f4 G = sp(gw.g[u]);
                    if (j == 0) a0v = __builtin_elementwise_fma(G, P, a0v);
                    if (j == 1) a1v = __builtin_elementwise_fma(G, P, a1v);
                    if (j == 2) a2v = __builtin_elementwise_fma(G, P, a2v);
                    if (j == 3) a3v = __builtin_elementwise_fma(G, P, a3v);
                }
            }
        }
        hS[hs][4 * cg + 0] = a0v;                // conflict-free b128 writes
        hS[hs][4 * cg + 1] = a1v;
        hS[hs][4 * cg + 2] = a2v;
        hS[hs][4 * cg + 3] = a3v;
    };

    // ---- warmup: stage local rows [0,42) -> slots 6..47 (f4 66..527)
    #pragma unroll
    for (int k = 0; k < 2; ++k) {
        int idx = (k << 8) + tid;
        if (idx < 42 * RAWP) {                   // 462
            int o = idx / RAWP, c4 = idx - o * RAWP;
            int db = 6 * RAWP + (k << 8) + (tid & ~63);
            dma1(0, db, R0 + o, c4);
            dma1(1, db, R0 + o, c4);
        }
    }
    asm volatile("s_waitcnt vmcnt(0)" ::: "memory");
    __builtin_amdgcn_s_barrier();
    FENCE();

    // ---- main loop: 8 iterations of 32 output rows
    double tsum = 0.0;
    const int c  = tid & 31;
    const int rb = (tid >> 5) * 4;               // 0,4,...,28

    for (int i = 0; i < NIT; ++i) {
        if (i >= 1 && i <= NIT - 2) dma_half(i, 0);  // batch A: hides h+v

        // h-conv: iter 0 = local rows [0,42) (336 tasks); else [32i+10,+42).
        const int rbm = (i == 0) ? 6 : ((32 * i + 16) % RAWR);
        const int bm  = (i == 0) ? 0 : ((32 * i + 10) % HSR);
        {
            const int cg = (tid >> 3) & 7;
            const int o  = (tid & 7) | ((tid >> 6) << 3);
            htask(o, cg, rbm, bm);
            if (i == 0) {
                if (tid < 64) htask(32 + (tid & 7), (tid >> 3) & 7, rbm, bm);
                if (tid < 16) htask(40 + (tid & 1), (tid >> 1) & 7, rbm, bm);
            }
        }
        asm volatile("s_waitcnt lgkmcnt(0)" ::: "memory");  // publish hS
        __builtin_amdgcn_s_barrier();            // NO vmcnt drain here
        FENCE();
        if (i == 0) dma_half(0, 0);              // iter-0 A: slots busy pre-mid
        if (i <= NIT - 2) dma_half(i, 1);        // batch B: hides under v

        // v-conv + SSIM epilogue: 1 col x 4 rows per thread.
        const int vb = (32 * i) % HSR;
        f4 A[4];
        #pragma unroll
        for (int j = 0; j < 4; ++j) A[j] = sp(0.f);
        #pragma unroll
        for (int k = 0; k < 14; ++k) {
            int s = vb + rb + k; if (s >= HSR) s -= HSR;
            f4 v = hS[s][c];                     // one ds_read_b128 per tap-row
            #pragma unroll
            for (int j = 0; j < 4; ++j) {
                int u = k - j;
                if (u >= 0 && u < 11) {
                    f4 G = sp(gw.g[u]);
                    A[j] = __builtin_elementwise_fma(G, v, A[j]);
                }
            }
        }
        const float C1 = 1.0e-4f;
        const float C2 = 9.0e-4f;
        float nn[4], dd[4];
        #pragma unroll
        for (int j = 0; j < 4; ++j) {
            f4 v = A[j];
            float t1 = v.x + 1.f, t2 = v.y + 1.f;        // 2*mu1, 2*mu2
            float num1 = fmaf(t1 * t2, 0.5f, C1);        // 2*mu1*mu2 + C1
            float den1 = fmaf(fmaf(t2, t2, t1 * t1), 0.25f, C1);
            float num2 = fmaf(v.w - v.x * v.y, 0.5f, C2);       // 2*sig12 + C2
            float den2 = fmaf(v.z - fmaf(v.x, v.x, v.y * v.y), 0.25f, C2);
            bool valid = (R0 + 32 * i + rb + j < OH) & (C0 + c < OW);
            nn[j] = valid ? num1 * num2 : 0.f;   // clamped-junk rows land here
            dd[j] = valid ? den1 * den2 : 1.f;   // and are replaced -> safe
        }
        // 1 divide / 4 outputs via common denominator
        // (dd >= C1*C2 ~ 1e-7; 4-products >= ~6e-29 stay normal in f32)
        float d01 = dd[0] * dd[1], d23 = dd[2] * dd[3];
        float s01 = fmaf(nn[0], dd[1], nn[1] * dd[0]);
        float s23 = fmaf(nn[2], dd[3], nn[3] * dd[2]);
        tsum += (double)(fmaf(s01, d23, s23 * d01) / (d01 * d23));

        // end-of-iter: drain this iter's DMA (A flew over h+v, B over v),
        // and protect hS/raw rings before next iter overwrites.
        asm volatile("s_waitcnt vmcnt(0) lgkmcnt(0)" ::: "memory");
        __builtin_amdgcn_s_barrier();
        FENCE();
    }

    // block reduction (double) + one f64 atomic into a strided slot
    #pragma unroll
    for (int off = 32; off > 0; off >>= 1)
        tsum += __shfl_down(tsum, off, 64);
    if ((tid & 63) == 0) wsum[tid >> 6] = tsum;
    __syncthreads();
    if (tid == 0) {
        int slot = (blockIdx.x + blockIdx.y * GX + blockIdx.z * GX * 2)
                   & (NSLOT - 1);
        atomicAdd(&acc[slot * 8], wsum[0] + wsum[1] + wsum[2] + wsum[3]);
    }
}

__global__ void ssim_finalize(const double* __restrict__ acc,
                              float* __restrict__ out) {
    int lane = threadIdx.x;                      // 64 threads, one slot each
    double t = acc[lane * 8];
    #pragma unroll
    for (int off = 32; off > 0; off >>= 1)
        t += __shfl_down(t, off, 64);
    if (lane == 0)
        out[0] = (float)(t * (1.0 / (double)((long long)NC * OH * OW)));
}

extern "C" void kernel_launch(void* const* d_in, const int* in_sizes, int n_in,
                              void* d_out, int out_size, void* d_ws, size_t ws_size,
                              hipStream_t stream) {
    const float* X = (const float*)d_in[0];
    const float* Y = (const float*)d_in[1];
    float* out = (float*)d_out;
    double* acc = (double*)d_ws;                 // 64 slots x 64 B = 4 KB

    // d_ws is re-poisoned to 0xAA before every timed launch: zero the slots.
    hipMemsetAsync(d_ws, 0, NSLOT * 64, stream);

    // Gaussian weights (win=11, sigma=1.5), computed in f64, passed by value.
    GaussW gw;
    {
        double g[11], s = 0.0;
        for (int i = 0; i < 11; ++i) {
            double d = (double)(i - 5);
            g[i] = exp(-d * d / (2.0 * 1.5 * 1.5));
            s += g[i];
        }
        for (int i = 0; i < 11; ++i) gw.g[i] = (float)(g[i] / s);
    }

    dim3 grid(GX, 2, NC);
    ssim_kernel<<<grid, dim3(256), 0, stream>>>(X, Y, acc, gw);
    ssim_finalize<<<1, dim3(64), 0, stream>>>(acc, out);
}